// Round 18
// baseline (61018.085 us; speedup 1.0000x reference)
//
#include <hip/hip_runtime.h>
#include <math.h>

// SocialLSTM round 18: revert to R14 (last-known-good: 55.3ms, absmax
// 4.88e-4 bit-deterministic) + ONE safe change: h1[p] register reuse.
// R16/R17's quad-layout rewrite produced garbage twice (absmax 0.37/0.75
// vs output scale ~0.06) and is abandoned. Here: phase A already holds
// each thread's h1[p] slice (elements 40*tid..40*tid+39 + 2 tail) in
// registers (hv/hv2); phase C pass 2 re-stages LDS from those registers
// instead of reloading from global -> read rounds 4 -> 3 per step.
// LDS chunk position for element e: OFF_H + (e>>10)*HROW +
// 36*((e&1023)>>5) + ((e&1023)&31) — identical algebra to R14's SSTQ.
// Everything else byte-identical to R14 (sc0 reads, fence-free barrier,
// literal-index register weights, bf16-packed W_te).

#define NBLK 256
#define NTHR 512
#define HTHR 256
#define SEQ  1024
#define HID  1024
#define EMB  512
#define NAG  21
#define NH   21504   // NAG*HID

// ws float offsets
#define IE_OFF  0
#define H0_OFF  11010048                   // SEQ*NAG*EMB
#define H1_OFF  (H0_OFF + 2*NH)
#define TE_OFF  (H1_OFF + 2*NH)
#define BAR_OFF (TE_OFF + 512)
#define ZTOT    (4*NH + 512 + 1024)       // bars region 1024 u32

// LDS float offsets. Activations in 32-float chunks at stride 36.
#define HROW   1152                        // 32 chunks * 36
#define IEROW  576                         // 16 chunks * 36
#define OFF_H    0                         // 21 * 1152 = 24192
#define OFF_IE   24192                     // 21 * 576  = 12096
#define OFF_TE   36288                     // 576
#define OFF_PART 36864                     // 21 * 144 (stride 9 per row-entry)
#define OFF_B0   39888                     // 16
#define OFF_B1   39904                     // 16
#define OFF_RED  39920                     // 16 (block_sum2: 8 waves x 2)
#define OFF_ABT  39936                     // 1
#define LDS_F    39952                     // 159,808 B -> 1 block/CU

// repetition macros: literal indices (SROA-promotable)
#define REP4(M)  M(0) M(1) M(2) M(3)
#define REP8(M)  REP4(M) M(4) M(5) M(6) M(7)
#define REP10(M) REP8(M) M(8) M(9)
#define REP16(M) REP8(M) M(8) M(9) M(10) M(11) M(12) M(13) M(14) M(15)
#define REP40(M) REP16(M) M(16) M(17) M(18) M(19) M(20) M(21) M(22) M(23) \
  M(24) M(25) M(26) M(27) M(28) M(29) M(30) M(31) M(32) M(33) M(34) M(35) \
  M(36) M(37) M(38) M(39)

typedef unsigned u32x4 __attribute__((ext_vector_type(4)));
typedef unsigned u32x2 __attribute__((ext_vector_type(2)));

struct Params {
  const float *x, *W_ie, *b_ie, *W_te, *b_te;
  const float *W_ih0, *W_hh0, *b_ih0, *b_hh0;
  const float *W_ih1, *W_hh1, *b_ih1, *b_hh1;
  const float *W_out, *b_out;
  float *out, *ws;
};

__device__ __forceinline__ float sigf(float v) { return 1.0f / (1.0f + expf(-v)); }

__device__ __forceinline__ float ald(const float* p) {
  return __hip_atomic_load(p, __ATOMIC_RELAXED, __HIP_MEMORY_SCOPE_AGENT);
}
__device__ __forceinline__ void ast(float* p, float v) {
  __hip_atomic_store(p, v, __ATOMIC_RELAXED, __HIP_MEMORY_SCOPE_AGENT);
}
// fp32 -> bf16 bits, round-to-nearest-even
__device__ __forceinline__ unsigned f2bf(float f) {
  unsigned u = __float_as_uint(f);
  return (u + 0x7fffu + ((u >> 16) & 1u)) >> 16;
}

__device__ __forceinline__ float block_sum(float v, float* red) {
  #pragma unroll
  for (int off = 32; off > 0; off >>= 1) v += __shfl_down(v, off, 64);
  const int w = threadIdx.x >> 6;
  if ((threadIdx.x & 63) == 0) red[w] = v;
  __syncthreads();
  float r = 0.f;
  #pragma unroll
  for (int i = 0; i < NTHR / 64; ++i) r += red[i];
  __syncthreads();
  return r;
}

// reduce two values in one barrier pair
__device__ __forceinline__ void block_sum2(float& v0, float& v1, float* red) {
  #pragma unroll
  for (int off = 32; off > 0; off >>= 1) {
    v0 += __shfl_down(v0, off, 64);
    v1 += __shfl_down(v1, off, 64);
  }
  const int w = threadIdx.x >> 6;
  if ((threadIdx.x & 63) == 0) { red[2 * w] = v0; red[2 * w + 1] = v1; }
  __syncthreads();
  v0 = ((red[0] + red[2]) + (red[4] + red[6])) + ((red[8] + red[10]) + (red[12] + red[14]));
  v1 = ((red[1] + red[3]) + (red[5] + red[7])) + ((red[9] + red[11]) + (red[13] + red[15]));
  __syncthreads();
}

// Fence-free 2-level tree barrier with 2-level RELEASE broadcast.
// bars[16+g*16]=group counter; bars[272]=root; bars[300]=abort;
// bars[512+g*32]=per-group release word (one 128B line per group).
__device__ __forceinline__ bool grid_barrier(unsigned* bars, unsigned ep, int b,
                                             float* ldsf) {
  __syncthreads();
  if (threadIdx.x == 0) {
    float abortv = 0.f;
    unsigned* grel = bars + 512 + ((unsigned)b >> 4) * 32;
    if (__hip_atomic_load(bars + 300, __ATOMIC_RELAXED, __HIP_MEMORY_SCOPE_AGENT) != 0u) {
      abortv = 1.f;
    } else {
      asm volatile("s_waitcnt vmcnt(0)" ::: "memory");
      unsigned* gc = bars + 16 + ((unsigned)b >> 4) * 16;
      unsigned old = __hip_atomic_fetch_add(gc, 1u, __ATOMIC_RELAXED, __HIP_MEMORY_SCOPE_AGENT);
      if (old == ep * 16u - 1u) {
        unsigned rold = __hip_atomic_fetch_add(bars + 16 + 256, 1u, __ATOMIC_RELAXED, __HIP_MEMORY_SCOPE_AGENT);
        if (rold == ep * 16u - 1u) {
          #pragma unroll
          for (int g = 0; g < 16; ++g)
            __hip_atomic_store(bars + 512 + g * 32, ep, __ATOMIC_RELAXED, __HIP_MEMORY_SCOPE_AGENT);
        }
      }
      unsigned spins = 0u;
      while (__hip_atomic_load(grel, __ATOMIC_RELAXED, __HIP_MEMORY_SCOPE_AGENT) < ep) {
        __builtin_amdgcn_s_sleep(8);
        if (++spins > 1000000u) {            // ~0.5s: declare failure, abort grid
          __hip_atomic_store(bars + 300, 1u, __ATOMIC_RELAXED, __HIP_MEMORY_SCOPE_AGENT);
          abortv = 1.f;
          break;
        }
        if ((spins & 255u) == 0u &&
            __hip_atomic_load(bars + 300, __ATOMIC_RELAXED, __HIP_MEMORY_SCOPE_AGENT) != 0u) {
          abortv = 1.f;
          break;
        }
      }
      asm volatile("" ::: "memory");
    }
    ldsf[OFF_ABT] = abortv;
  }
  __syncthreads();
  return ldsf[OFF_ABT] != 0.f;
}

__global__ void sl_init(float* ws) {
  int tid = blockIdx.x * blockDim.x + threadIdx.x;
  int stride = gridDim.x * blockDim.x;
  for (int i = tid; i < ZTOT; i += stride) ws[H0_OFF + i] = 0.0f;
}

// ie[t,a,e] = relu( sum_{k<43} x[t,k]*W_ie[e,k] + x[t,43+a]*W_ie[e,43] + b_ie[e] )
__global__ void sl_ie(const float* __restrict__ x, const float* __restrict__ W_ie,
                      const float* __restrict__ b_ie, float* __restrict__ ws) {
  const int t = blockIdx.x;
  const int tid = threadIdx.x;
  __shared__ float xs[64];
  __shared__ float base[EMB];
  __shared__ float w43[EMB];
  if (tid < 64) xs[tid] = x[t * 64 + tid];
  __syncthreads();
  for (int e = tid; e < EMB; e += HTHR) {
    const float* wr = W_ie + e * 44;
    float acc = b_ie[e];
    #pragma unroll
    for (int k = 0; k < 43; ++k) acc += xs[k] * wr[k];
    base[e] = acc;
    w43[e] = wr[43];
  }
  __syncthreads();
  float* iep = ws + IE_OFF + (size_t)t * (NAG * EMB);
  for (int idx = tid; idx < NAG * EMB; idx += HTHR) {
    int a = idx >> 9, e = idx & 511;
    float v = base[e] + xs[43 + a] * w43[e];
    iep[idx] = v > 0.0f ? v : 0.0f;
  }
}

// staging macros: contiguous per-lane slice (10 x dwordx4 + 1 x dwordx2),
// agent-coherent (sc0), fully pipelined. Same as R14.
#define SLDQ(q) { const float4* ap = hs4 + 10 * tid + (q); \
  asm volatile("global_load_dwordx4 %0, %1, off sc0" : "=v"(sv[q]) : "v"(ap)); }
#define SSTQ(q) { int i0 = 40 * tid + 4 * (q); int aa = i0 >> 10; int cc = i0 & 1023; \
  float2 f0v; f0v.x = __uint_as_float(sv[q][0]); f0v.y = __uint_as_float(sv[q][1]); \
  *(float2*)&lds[OFF_H + aa * HROW + 36 * (cc >> 5) + (cc & 31)] = f0v; \
  int i1 = i0 + 2; int a1i = i1 >> 10; int c1i = i1 & 1023; \
  float2 f1v; f1v.x = __uint_as_float(sv[q][2]); f1v.y = __uint_as_float(sv[q][3]); \
  *(float2*)&lds[OFF_H + a1i * HROW + 36 * (c1i >> 5) + (c1i & 31)] = f1v; }
#define STAGE_H(SRC) { \
  const float4* hs4 = (const float4*)(SRC); \
  u32x4 sv[10]; u32x2 sv2; \
  REP10(SLDQ) \
  { const float* ap = (const float*)(SRC) + 20480 + 2 * tid; \
    asm volatile("global_load_dwordx2 %0, %1, off sc0" : "=v"(sv2) : "v"(ap)); } \
  asm volatile("s_waitcnt vmcnt(0)" ::: "memory"); \
  __builtin_amdgcn_sched_barrier(0); \
  REP10(SSTQ) \
  { int i2 = 20480 + 2 * tid; int aa = i2 >> 10; int cc = i2 & 1023; float2 ff; \
    ff.x = __uint_as_float(sv2[0]); ff.y = __uint_as_float(sv2[1]); \
    *(float2*)&lds[OFF_H + aa * HROW + 36 * (cc >> 5) + (cc & 31)] = ff; } }

__global__ void __launch_bounds__(NTHR)
__attribute__((amdgpu_waves_per_eu(2, 2)))
sl_main(Params P) {
  const int b = blockIdx.x;
  const int tid = threadIdx.x;
  float* ws = P.ws;
  float* wste = ws + TE_OFF;
  unsigned* bars = (unsigned*)(ws + BAR_OFF);

  __shared__ float lds[LDS_F];

  const int lane = tid & 63;
  const int wav  = tid >> 6;    // 0..7
  const int n    = tid & 15;    // gate-row-in-16 (gate = n>>2, col j = n&3)
  const int ks   = tid >> 4;    // 0..31 K-slice
  const int grow = (n >> 2) * HID + 4 * b + (n & 3);

  // ---- one-time weight loads into registers (all indices LITERAL) ----
  float w0[64];   // layer-0 combined row [W_ih0 | W_hh0], 64-float slice 64*ks
  {
    const float* s0 = (ks < 16) ? (P.W_ih0 + (size_t)grow * 1024 + 64 * ks)
                                : (P.W_hh0 + (size_t)grow * 1024 + 64 * (ks - 16));
#define LW0(i) { float4 v = *(const float4*)(s0 + 4*(i)); \
    w0[4*(i)] = v.x; w0[4*(i)+1] = v.y; w0[4*(i)+2] = v.z; w0[4*(i)+3] = v.w; }
    REP16(LW0)
  }
  float w1a[32], w1b[32];   // layer-1 rows, 32-float slice 32*ks
  {
    const float* s1 = P.W_ih1 + (size_t)grow * 1024 + 32 * ks;
    const float* s2 = P.W_hh1 + (size_t)grow * 1024 + 32 * ks;
#define LW1(i) { float4 v = *(const float4*)(s1 + 4*(i)); \
    w1a[4*(i)] = v.x; w1a[4*(i)+1] = v.y; w1a[4*(i)+2] = v.z; w1a[4*(i)+3] = v.w; \
    float4 u = *(const float4*)(s2 + 4*(i)); \
    w1b[4*(i)] = u.x; w1b[4*(i)+1] = u.y; w1b[4*(i)+2] = u.z; w1b[4*(i)+3] = u.w; }
    REP8(LW1)
  }
  // W_te rows {2b,2b+1} packed bf16 pairs; element k maps to float index
  // I(k) = 40*tid + k (k<40), 20480 + 2*tid + (k-40) (k=40,41).
  unsigned wtepk[42];
  {
    const float* wt0 = P.W_te + (size_t)(2 * b) * NH;
#define LWT(k) { float f0 = wt0[40*tid + (k)]; float f1 = wt0[NH + 40*tid + (k)]; \
    wtepk[k] = f2bf(f0) | (f2bf(f1) << 16); }
    REP40(LWT)
    { int ix = 20480 + 2 * tid;
      wtepk[40] = f2bf(wt0[ix])     | (f2bf(wt0[NH + ix]) << 16);
      wtepk[41] = f2bf(wt0[ix + 1]) | (f2bf(wt0[NH + ix + 1]) << 16); }
  }
  const float bte0 = P.b_te[2 * b], bte1 = P.b_te[2 * b + 1];
  const float bout = P.b_out[0];
  if (tid < 16) {
    int gr = (tid >> 2) * HID + 4 * b + (tid & 3);
    lds[OFF_B0 + tid] = P.b_ih0[gr] + P.b_hh0[gr];
    lds[OFF_B1 + tid] = P.b_ih1[gr] + P.b_hh1[gr];
  }
  __syncthreads();

  // phase-B LDS base: K = [ie 512 | te 512 | h0 1024] in 64-float slices
  int bB_base, bB_astep;
  if (ks < 8)       { bB_base = OFF_IE + 72 * ks;        bB_astep = IEROW; }
  else if (ks < 16) { bB_base = OFF_TE + 72 * (ks - 8);  bB_astep = 0;     }
  else              { bB_base = OFF_H  + 72 * (ks - 16); bB_astep = HROW;  }
  const int bC_base = OFF_H + 36 * ks;

  float c0r = 0.f, c1r = 0.f, h0r = 0.f, h1r = 0.f;
  unsigned ep = 0;

  for (int t = 0; t < SEQ; ++t) {
    const int p = t & 1;
    u32x4 hv[10]; u32x2 hv2;   // h1[p] slice: lives phase A -> phase C pass 2

    // ---------- phase A: te rows {2b,2b+1}; block0: out[t-1] ----------
    {
      const float* h1base = ws + H1_OFF + p * NH;
      const float4* h1f4 = (const float4*)h1base;
#define PALD(q) { const float4* ap = h1f4 + 10 * tid + (q); \
      asm volatile("global_load_dwordx4 %0, %1, off sc0" : "=v"(hv[q]) : "v"(ap)); }
      REP10(PALD)
      { const float* ap = h1base + 20480 + 2 * tid;
        asm volatile("global_load_dwordx2 %0, %1, off sc0" : "=v"(hv2) : "v"(ap)); }
      asm volatile("s_waitcnt vmcnt(0)" ::: "memory");
      __builtin_amdgcn_sched_barrier(0);
      float a0 = 0.f, a1 = 0.f;
#define PHAF(k) { float hvf = __uint_as_float(hv[(k)>>2][(k)&3]); \
      a0 += __uint_as_float(wtepk[k] << 16) * hvf; \
      a1 += __uint_as_float(wtepk[k] & 0xffff0000u) * hvf; }
      REP40(PHAF)
      { float hvf = __uint_as_float(hv2[0]);
        a0 += __uint_as_float(wtepk[40] << 16) * hvf;
        a1 += __uint_as_float(wtepk[40] & 0xffff0000u) * hvf; }
      { float hvf = __uint_as_float(hv2[1]);
        a0 += __uint_as_float(wtepk[41] << 16) * hvf;
        a1 += __uint_as_float(wtepk[41] & 0xffff0000u) * hvf; }
      block_sum2(a0, a1, &lds[OFF_RED]);
      if (tid == 0) {
        float v0 = a0 + bte0, v1 = a1 + bte1;
        v0 = v0 > 0.f ? v0 : 0.f;
        v1 = v1 > 0.f ? v1 : 0.f;
        unsigned long long tv = ((unsigned long long)__float_as_uint(v1) << 32)
                              | (unsigned long long)__float_as_uint(v0);
        __hip_atomic_store((unsigned long long*)(wste + 2 * b), tv,
                           __ATOMIC_RELAXED, __HIP_MEMORY_SCOPE_AGENT);
      }
      if (b == 0) {
        float ao = 0.f;
        if (t > 0) {
          const float4* wo4 = (const float4*)P.W_out;
#define PAO(q) { float4 wv = wo4[10 * tid + (q)]; \
          ao += wv.x * __uint_as_float(hv[q][0]) + wv.y * __uint_as_float(hv[q][1]) \
              + wv.z * __uint_as_float(hv[q][2]) + wv.w * __uint_as_float(hv[q][3]); }
          REP10(PAO)
          const float* woe = P.W_out + 20480 + 2 * tid;
          ao += woe[0] * __uint_as_float(hv2[0]) + woe[1] * __uint_as_float(hv2[1]);
        }
        ao = block_sum(ao, &lds[OFF_RED]);
        if (tid == 0 && t > 0) P.out[t - 1] = ao + bout;
      }
    }
    ++ep; if (grid_barrier(bars, ep, b, lds)) break;

    // ---------- phase B: layer-0 ----------
    {
      float tev;
      { const float* ap = wste + tid;
        asm volatile("global_load_dword %0, %1, off sc0" : "=v"(tev) : "v"(ap)); }
      // stage ie[t] (read-only, cached, compiler-managed loads)
      {
        const float4* iep4 =
            (const float4*)(ws + IE_OFF + (size_t)t * (NAG * EMB));
        float4 t40 = iep4[tid];
        float4 t41 = iep4[tid + 512];
        float4 t42 = iep4[tid + 1024];
        float4 t43 = iep4[tid + 1536];
        float4 t44 = iep4[tid + 2048];
        float4 t45 = t40;
        const bool g5 = tid < 128;
        if (g5) t45 = iep4[tid + 2560];
#define IEST(k, reg) { int i4 = tid + 512*(k); int aa = i4 >> 7; int k4 = i4 & 127; \
        *(float4*)&lds[OFF_IE + aa * IEROW + 36 * (k4 >> 3) + 4 * (k4 & 7)] = reg; }
        IEST(0, t40) IEST(1, t41) IEST(2, t42) IEST(3, t43) IEST(4, t44)
        if (g5) IEST(5, t45)
      }
      STAGE_H(ws + H0_OFF + p * NH)
      lds[OFF_TE + 36 * (tid >> 5) + (tid & 31)] = tev;
      __syncthreads();

      int laddr = bB_base;
      for (int a = 0; a < NAG; ++a) {
        float ac0 = 0.f, ac1 = 0.f, ac2 = 0.f, ac3 = 0.f;
#define DOTB(j, ac, woff, zoff) { float4 z = *(const float4*)&lds[laddr + (zoff) + 4*(j)]; \
        ac += w0[(woff)+4*(j)]*z.x;   ac += w0[(woff)+4*(j)+1]*z.y; \
        ac += w0[(woff)+4*(j)+2]*z.z; ac += w0[(woff)+4*(j)+3]*z.w; }
        DOTB(0, ac0, 0, 0)  DOTB(1, ac1, 0, 0)  DOTB(2, ac2, 0, 0)  DOTB(3, ac3, 0, 0)
        DOTB(4, ac0, 0, 0)  DOTB(5, ac1, 0, 0)  DOTB(6, ac2, 0, 0)  DOTB(7, ac3, 0, 0)
        DOTB(0, ac0, 32, 36) DOTB(1, ac1, 32, 36) DOTB(2, ac2, 32, 36) DOTB(3, ac3, 32, 36)
        DOTB(4, ac0, 32, 36) DOTB(5, ac1, 32, 36) DOTB(6, ac2, 32, 36) DOTB(7, ac3, 32, 36)
        float acc = (ac0 + ac1) + (ac2 + ac3);
        acc += __shfl_xor(acc, 16);
        acc += __shfl_xor(acc, 32);
        if (lane < 16) lds[OFF_PART + a * 144 + n * 9 + wav] = acc;
        laddr += bB_astep;
      }
      __syncthreads();
      if (tid < 84) {
        int a = tid >> 2, j = tid & 3;
        const float* pp = &lds[OFF_PART + a * 144];
        float gv0, gv1, gv2, gv3;
#define GATE(base, gg, gv) { float s = lds[(base) + 4*(gg) + j]; \
        s += pp[(4*(gg)+j)*9+0] + pp[(4*(gg)+j)*9+1] + pp[(4*(gg)+j)*9+2] + pp[(4*(gg)+j)*9+3]; \
        s += pp[(4*(gg)+j)*9+4] + pp[(4*(gg)+j)*9+5] + pp[(4*(gg)+j)*9+6] + pp[(4*(gg)+j)*9+7]; \
        gv = s; }
        GATE(OFF_B0, 0, gv0) GATE(OFF_B0, 1, gv1) GATE(OFF_B0, 2, gv2) GATE(OFF_B0, 3, gv3)
        float cn = sigf(gv1) * c0r + sigf(gv0) * tanhf(gv2);
        float hn = sigf(gv3) * tanhf(cn);
        c0r = cn; h0r = hn;
        ast(ws + H0_OFF + (p ^ 1) * NH + a * HID + 4 * b + j, hn);
      }
    }
    ++ep; if (grid_barrier(bars, ep, b, lds)) break;

    // ---------- phase C: layer-1 (pass1: h0n x W_ih1; pass2: h1p x W_hh1) ----------
    {
      STAGE_H(ws + H0_OFF + (p ^ 1) * NH)
      __syncthreads();
      int laddr = bC_base;
      for (int a = 0; a < NAG; ++a) {
        float ac0 = 0.f, ac1 = 0.f;
#define DOTC(j, ac, W) { float4 z = *(const float4*)&lds[laddr + 4*(j)]; \
        ac += W[4*(j)]*z.x; ac += W[4*(j)+1]*z.y; ac += W[4*(j)+2]*z.z; ac += W[4*(j)+3]*z.w; }
        DOTC(0, ac0, w1a) DOTC(1, ac1, w1a) DOTC(2, ac0, w1a) DOTC(3, ac1, w1a)
        DOTC(4, ac0, w1a) DOTC(5, ac1, w1a) DOTC(6, ac0, w1a) DOTC(7, ac1, w1a)
        float acc = ac0 + ac1;
        acc += __shfl_xor(acc, 16);
        acc += __shfl_xor(acc, 32);
        if (lane < 16) lds[OFF_PART + a * 144 + n * 9 + wav] = acc;
        laddr += HROW;
      }
      __syncthreads();
      // h1[p] re-staging WITHOUT reload: reuse hv/hv2 from phase A.
      // Element e = 40*tid + 4q -> LDS chunk pos (same algebra as SSTQ).
      {
#define RST(q) { int i0 = 40 * tid + 4 * (q); int aa = i0 >> 10; int cc = i0 & 1023; \
        float4 ff; ff.x = __uint_as_float(hv[q][0]); ff.y = __uint_as_float(hv[q][1]); \
        ff.z = __uint_as_float(hv[q][2]); ff.w = __uint_as_float(hv[q][3]); \
        *(float4*)&lds[OFF_H + aa * HROW + 36 * (cc >> 5) + (cc & 31)] = ff; }
        REP10(RST)
        { int i2 = 20480 + 2 * tid; int aa = i2 >> 10; int cc = i2 & 1023; float2 ff;
          ff.x = __uint_as_float(hv2[0]); ff.y = __uint_as_float(hv2[1]);
          *(float2*)&lds[OFF_H + aa * HROW + 36 * (cc >> 5) + (cc & 31)] = ff; }
      }
      __syncthreads();
      laddr = bC_base;
      for (int a = 0; a < NAG; ++a) {
        float ac0 = 0.f, ac1 = 0.f;
        DOTC(0, ac0, w1b) DOTC(1, ac1, w1b) DOTC(2, ac0, w1b) DOTC(3, ac1, w1b)
        DOTC(4, ac0, w1b) DOTC(5, ac1, w1b) DOTC(6, ac0, w1b) DOTC(7, ac1, w1b)
        float acc = ac0 + ac1;
        acc += __shfl_xor(acc, 16);
        acc += __shfl_xor(acc, 32);
        if (lane < 16) lds[OFF_PART + a * 144 + n * 9 + wav] += acc;
        laddr += HROW;
      }
      __syncthreads();
      if (tid < 84) {
        int a = tid >> 2, j = tid & 3;
        const float* pp = &lds[OFF_PART + a * 144];
        float gv0, gv1, gv2, gv3;
        GATE(OFF_B1, 0, gv0) GATE(OFF_B1, 1, gv1) GATE(OFF_B1, 2, gv2) GATE(OFF_B1, 3, gv3)
        float cn = sigf(gv1) * c1r + sigf(gv0) * tanhf(gv2);
        float hn = sigf(gv3) * tanhf(cn);
        c1r = cn; h1r = hn;
        ast(ws + H1_OFF + (p ^ 1) * NH + a * HID + 4 * b + j, hn);
      }
    }
    ++ep; if (grid_barrier(bars, ep, b, lds)) break;
  }

  // ---------- epilogue: out[S-1] + final states from registers ----------
  if (b == 0) {
    const float* h1s = ws + H1_OFF;   // final h1 in buffer 0 (S even)
    float ao = 0.f;
    #pragma unroll
    for (int k = 0; k < 42; ++k)
      ao += P.W_out[512 * k + tid] * ald(h1s + 512 * k + tid);
    ao = block_sum(ao, &lds[OFF_RED]);
    if (tid == 0) P.out[SEQ - 1] = ao + bout;
  }
  if (tid < 84) {
    int a = tid >> 2, j = tid & 3;
    int idx = a * HID + 4 * b + j;
    P.out[SEQ + idx]          = h0r;
    P.out[SEQ + NH + idx]     = h1r;
    P.out[SEQ + 2*NH + idx]   = c0r;
    P.out[SEQ + 3*NH + idx]   = c1r;
  }
}

extern "C" void kernel_launch(void* const* d_in, const int* in_sizes, int n_in,
                              void* d_out, int out_size, void* d_ws, size_t ws_size,
                              hipStream_t stream) {
  (void)in_sizes; (void)n_in; (void)out_size; (void)ws_size;
  Params P;
  P.x     = (const float*)d_in[0];
  P.W_ie  = (const float*)d_in[1];
  P.b_ie  = (const float*)d_in[2];
  P.W_te  = (const float*)d_in[3];
  P.b_te  = (const float*)d_in[4];
  P.W_ih0 = (const float*)d_in[5];
  P.W_hh0 = (const float*)d_in[6];
  P.b_ih0 = (const float*)d_in[7];
  P.b_hh0 = (const float*)d_in[8];
  P.W_ih1 = (const float*)d_in[9];
  P.W_hh1 = (const float*)d_in[10];
  P.b_ih1 = (const float*)d_in[11];
  P.b_hh1 = (const float*)d_in[12];
  P.W_out = (const float*)d_in[13];
  P.b_out = (const float*)d_in[14];
  P.out   = (float*)d_out;
  P.ws    = (float*)d_ws;

  sl_init<<<64, HTHR, 0, stream>>>((float*)d_ws);
  sl_ie<<<SEQ, HTHR, 0, stream>>>(P.x, P.W_ie, P.b_ie, (float*)d_ws);

  void* args[] = { &P };
  hipLaunchCooperativeKernel((const void*)sl_main, dim3(NBLK), dim3(NTHR),
                             args, 0, stream);
}

// Round 19
// 52499.829 us; speedup vs baseline: 1.1623x; 1.1623x over previous
//
#include <hip/hip_runtime.h>
#include <math.h>

// SocialLSTM round 19: bf16 h-state TRANSPORT (internal state stays fp32).
// R18 evidence: fetch floor ~26MB/step is invariant to cache bits and read
// rounds; it scales (if anything) with communicated BYTES. Halve them:
// h0/h1 cross-block buffers are bf16. Writers gather 4 lanes' bf16 via
// shfl_down -> one aligned 8B agent-atomic store per agent. Readers: 21 u32
// per thread (5x dwordx4 + 1 dword, sc0) = R14's proven 40+2-element slice
// mapping (W_te/W_out indexing unchanged); unpack to fp32 LDS. c/h kept
// fp32 in registers; barrier/weights/structure identical to R18 (passed,
// absmax 4.88e-4).

#define NBLK 256
#define NTHR 512
#define HTHR 256
#define SEQ  1024
#define HID  1024
#define EMB  512
#define NAG  21
#define NH   21504   // NAG*HID

// ws float offsets. Comm region now bf16: 4 h-buffers x 10752 u32.
#define IE_OFF  0
#define H0_OFF  11010048                   // SEQ*NAG*EMB
#define TE_OFF  (H0_OFF + 43008)           // after 4x10752 u32 h-buffers
#define BAR_OFF (TE_OFF + 512)
#define ZTOT    (43008 + 512 + 1024)

// LDS float offsets. Activations in 32-float chunks at stride 36.
#define HROW   1152                        // 32 chunks * 36
#define IEROW  576                         // 16 chunks * 36
#define OFF_H    0                         // 21 * 1152 = 24192
#define OFF_IE   24192                     // 21 * 576  = 12096
#define OFF_TE   36288                     // 576
#define OFF_PART 36864                     // 21 * 144 (stride 9 per row-entry)
#define OFF_B0   39888                     // 16
#define OFF_B1   39904                     // 16
#define OFF_RED  39920                     // 16
#define OFF_ABT  39936                     // 1
#define LDS_F    39952                     // 159,808 B -> 1 block/CU

// repetition macros: literal indices (SROA-promotable)
#define REP4(M)  M(0) M(1) M(2) M(3)
#define REP5(M)  REP4(M) M(4)
#define REP8(M)  REP4(M) M(4) M(5) M(6) M(7)
#define REP16(M) REP8(M) M(8) M(9) M(10) M(11) M(12) M(13) M(14) M(15)
#define REP20(M) REP16(M) M(16) M(17) M(18) M(19)
#define REP40(M) REP20(M) M(20) M(21) M(22) M(23) \
  M(24) M(25) M(26) M(27) M(28) M(29) M(30) M(31) M(32) M(33) M(34) M(35) \
  M(36) M(37) M(38) M(39)

typedef unsigned u32x4 __attribute__((ext_vector_type(4)));

struct Params {
  const float *x, *W_ie, *b_ie, *W_te, *b_te;
  const float *W_ih0, *W_hh0, *b_ih0, *b_hh0;
  const float *W_ih1, *W_hh1, *b_ih1, *b_hh1;
  const float *W_out, *b_out;
  float *out, *ws;
};

__device__ __forceinline__ float sigf(float v) { return 1.0f / (1.0f + expf(-v)); }
__device__ __forceinline__ float bfl(unsigned u) { return __uint_as_float(u << 16); }
__device__ __forceinline__ float bfh(unsigned u) { return __uint_as_float(u & 0xffff0000u); }
// fp32 -> bf16 bits, round-to-nearest-even
__device__ __forceinline__ unsigned f2bf(float f) {
  unsigned u = __float_as_uint(f);
  return (u + 0x7fffu + ((u >> 16) & 1u)) >> 16;
}

__device__ __forceinline__ float block_sum(float v, float* red) {
  #pragma unroll
  for (int off = 32; off > 0; off >>= 1) v += __shfl_down(v, off, 64);
  const int w = threadIdx.x >> 6;
  if ((threadIdx.x & 63) == 0) red[w] = v;
  __syncthreads();
  float r = 0.f;
  #pragma unroll
  for (int i = 0; i < NTHR / 64; ++i) r += red[i];
  __syncthreads();
  return r;
}

__device__ __forceinline__ void block_sum2(float& v0, float& v1, float* red) {
  #pragma unroll
  for (int off = 32; off > 0; off >>= 1) {
    v0 += __shfl_down(v0, off, 64);
    v1 += __shfl_down(v1, off, 64);
  }
  const int w = threadIdx.x >> 6;
  if ((threadIdx.x & 63) == 0) { red[2 * w] = v0; red[2 * w + 1] = v1; }
  __syncthreads();
  v0 = ((red[0] + red[2]) + (red[4] + red[6])) + ((red[8] + red[10]) + (red[12] + red[14]));
  v1 = ((red[1] + red[3]) + (red[5] + red[7])) + ((red[9] + red[11]) + (red[13] + red[15]));
  __syncthreads();
}

// Fence-free 2-level tree barrier with 2-level release broadcast (proven).
__device__ __forceinline__ bool grid_barrier(unsigned* bars, unsigned ep, int b,
                                             float* ldsf) {
  __syncthreads();
  if (threadIdx.x == 0) {
    float abortv = 0.f;
    unsigned* grel = bars + 512 + ((unsigned)b >> 4) * 32;
    if (__hip_atomic_load(bars + 300, __ATOMIC_RELAXED, __HIP_MEMORY_SCOPE_AGENT) != 0u) {
      abortv = 1.f;
    } else {
      asm volatile("s_waitcnt vmcnt(0)" ::: "memory");
      unsigned* gc = bars + 16 + ((unsigned)b >> 4) * 16;
      unsigned old = __hip_atomic_fetch_add(gc, 1u, __ATOMIC_RELAXED, __HIP_MEMORY_SCOPE_AGENT);
      if (old == ep * 16u - 1u) {
        unsigned rold = __hip_atomic_fetch_add(bars + 16 + 256, 1u, __ATOMIC_RELAXED, __HIP_MEMORY_SCOPE_AGENT);
        if (rold == ep * 16u - 1u) {
          #pragma unroll
          for (int g = 0; g < 16; ++g)
            __hip_atomic_store(bars + 512 + g * 32, ep, __ATOMIC_RELAXED, __HIP_MEMORY_SCOPE_AGENT);
        }
      }
      unsigned spins = 0u;
      while (__hip_atomic_load(grel, __ATOMIC_RELAXED, __HIP_MEMORY_SCOPE_AGENT) < ep) {
        __builtin_amdgcn_s_sleep(8);
        if (++spins > 1000000u) {
          __hip_atomic_store(bars + 300, 1u, __ATOMIC_RELAXED, __HIP_MEMORY_SCOPE_AGENT);
          abortv = 1.f;
          break;
        }
        if ((spins & 255u) == 0u &&
            __hip_atomic_load(bars + 300, __ATOMIC_RELAXED, __HIP_MEMORY_SCOPE_AGENT) != 0u) {
          abortv = 1.f;
          break;
        }
      }
      asm volatile("" ::: "memory");
    }
    ldsf[OFF_ABT] = abortv;
  }
  __syncthreads();
  return ldsf[OFF_ABT] != 0.f;
}

__global__ void sl_init(float* ws) {
  int tid = blockIdx.x * blockDim.x + threadIdx.x;
  int stride = gridDim.x * blockDim.x;
  for (int i = tid; i < ZTOT; i += stride) ws[H0_OFF + i] = 0.0f;
}

// ie[t,a,e] = relu( sum_{k<43} x[t,k]*W_ie[e,k] + x[t,43+a]*W_ie[e,43] + b_ie[e] )
__global__ void sl_ie(const float* __restrict__ x, const float* __restrict__ W_ie,
                      const float* __restrict__ b_ie, float* __restrict__ ws) {
  const int t = blockIdx.x;
  const int tid = threadIdx.x;
  __shared__ float xs[64];
  __shared__ float base[EMB];
  __shared__ float w43[EMB];
  if (tid < 64) xs[tid] = x[t * 64 + tid];
  __syncthreads();
  for (int e = tid; e < EMB; e += HTHR) {
    const float* wr = W_ie + e * 44;
    float acc = b_ie[e];
    #pragma unroll
    for (int k = 0; k < 43; ++k) acc += xs[k] * wr[k];
    base[e] = acc;
    w43[e] = wr[43];
  }
  __syncthreads();
  float* iep = ws + IE_OFF + (size_t)t * (NAG * EMB);
  for (int idx = tid; idx < NAG * EMB; idx += HTHR) {
    int a = idx >> 9, e = idx & 511;
    float v = base[e] + xs[43 + a] * w43[e];
    iep[idx] = v > 0.0f ? v : 0.0f;
  }
}

// bf16 h staging: per-thread 21 u32 = elements 40*tid..+39 and 20480+2*tid..+1
#define HBLD(q) { const u32x4* ap = (const u32x4*)(srcu + 20 * tid) + (q); \
  asm volatile("global_load_dwordx4 %0, %1, off sc0" : "=v"(sv[q]) : "v"(ap)); }
#define ST2(u, e0) { int aa = (e0) >> 10; int cc = (e0) & 1023; float2 f2v; \
  f2v.x = bfl(u); f2v.y = bfh(u); \
  *(float2*)&lds[OFF_H + aa * HROW + 36 * (cc >> 5) + (cc & 31)] = f2v; }
#define HBST(q) { ST2(sv[q][0], 40*tid + 8*(q)) ST2(sv[q][1], 40*tid + 8*(q)+2) \
  ST2(sv[q][2], 40*tid + 8*(q)+4) ST2(sv[q][3], 40*tid + 8*(q)+6) }
#define STAGE_HBF(SRCU) { \
  const unsigned* srcu = (SRCU); \
  u32x4 sv[5]; unsigned sv2; \
  REP5(HBLD) \
  { const unsigned* ap = srcu + 10240 + tid; \
    asm volatile("global_load_dword %0, %1, off sc0" : "=v"(sv2) : "v"(ap)); } \
  asm volatile("s_waitcnt vmcnt(0)" ::: "memory"); \
  __builtin_amdgcn_sched_barrier(0); \
  REP5(HBST) \
  ST2(sv2, 20480 + 2 * tid) }

__global__ void __launch_bounds__(NTHR)
__attribute__((amdgpu_waves_per_eu(2, 2)))
sl_main(Params P) {
  const int b = blockIdx.x;
  const int tid = threadIdx.x;
  float* ws = P.ws;
  float* wste = ws + TE_OFF;
  unsigned* hbase = (unsigned*)(ws + H0_OFF);   // [h0 p0|h0 p1|h1 p0|h1 p1] x10752 u32
  unsigned* bars = (unsigned*)(ws + BAR_OFF);

  __shared__ float lds[LDS_F];

  const int lane = tid & 63;
  const int wav  = tid >> 6;
  const int n    = tid & 15;
  const int ks   = tid >> 4;
  const int grow = (n >> 2) * HID + 4 * b + (n & 3);

  // ---- one-time weight loads into registers (all indices LITERAL) ----
  float w0[64];
  {
    const float* s0 = (ks < 16) ? (P.W_ih0 + (size_t)grow * 1024 + 64 * ks)
                                : (P.W_hh0 + (size_t)grow * 1024 + 64 * (ks - 16));
#define LW0(i) { float4 v = *(const float4*)(s0 + 4*(i)); \
    w0[4*(i)] = v.x; w0[4*(i)+1] = v.y; w0[4*(i)+2] = v.z; w0[4*(i)+3] = v.w; }
    REP16(LW0)
  }
  float w1a[32], w1b[32];
  {
    const float* s1 = P.W_ih1 + (size_t)grow * 1024 + 32 * ks;
    const float* s2 = P.W_hh1 + (size_t)grow * 1024 + 32 * ks;
#define LW1(i) { float4 v = *(const float4*)(s1 + 4*(i)); \
    w1a[4*(i)] = v.x; w1a[4*(i)+1] = v.y; w1a[4*(i)+2] = v.z; w1a[4*(i)+3] = v.w; \
    float4 u = *(const float4*)(s2 + 4*(i)); \
    w1b[4*(i)] = u.x; w1b[4*(i)+1] = u.y; w1b[4*(i)+2] = u.z; w1b[4*(i)+3] = u.w; }
    REP8(LW1)
  }
  // W_te rows {2b,2b+1} packed bf16 pairs; element k = 40*tid+k, tail 20480+2*tid
  unsigned wtepk[42];
  {
    const float* wt0 = P.W_te + (size_t)(2 * b) * NH;
#define LWT(k) { float f0 = wt0[40*tid + (k)]; float f1 = wt0[NH + 40*tid + (k)]; \
    wtepk[k] = f2bf(f0) | (f2bf(f1) << 16); }
    REP40(LWT)
    { int ix = 20480 + 2 * tid;
      wtepk[40] = f2bf(wt0[ix])     | (f2bf(wt0[NH + ix]) << 16);
      wtepk[41] = f2bf(wt0[ix + 1]) | (f2bf(wt0[NH + ix + 1]) << 16); }
  }
  const float bte0 = P.b_te[2 * b], bte1 = P.b_te[2 * b + 1];
  const float bout = P.b_out[0];
  if (tid < 16) {
    int gr = (tid >> 2) * HID + 4 * b + (tid & 3);
    lds[OFF_B0 + tid] = P.b_ih0[gr] + P.b_hh0[gr];
    lds[OFF_B1 + tid] = P.b_ih1[gr] + P.b_hh1[gr];
  }
  __syncthreads();

  // phase-B LDS base: K = [ie 512 | te 512 | h0 1024] in 64-float slices
  int bB_base, bB_astep;
  if (ks < 8)       { bB_base = OFF_IE + 72 * ks;        bB_astep = IEROW; }
  else if (ks < 16) { bB_base = OFF_TE + 72 * (ks - 8);  bB_astep = 0;     }
  else              { bB_base = OFF_H  + 72 * (ks - 16); bB_astep = HROW;  }
  const int bC_base = OFF_H + 36 * ks;

  float c0r = 0.f, c1r = 0.f, h0r = 0.f, h1r = 0.f;
  unsigned ep = 0;

  for (int t = 0; t < SEQ; ++t) {
    const int p = t & 1;
    u32x4 hv[5]; unsigned hv2;   // h1[p] bf16 slice: lives phase A -> C pass 2

    // ---------- phase A: te rows {2b,2b+1}; block0: out[t-1] ----------
    {
      const unsigned* h1u = hbase + 21504 + p * 10752;
#define PALD(q) { const u32x4* ap = (const u32x4*)(h1u + 20 * tid) + (q); \
      asm volatile("global_load_dwordx4 %0, %1, off sc0" : "=v"(hv[q]) : "v"(ap)); }
      REP5(PALD)
      { const unsigned* ap = h1u + 10240 + tid;
        asm volatile("global_load_dword %0, %1, off sc0" : "=v"(hv2) : "v"(ap)); }
      asm volatile("s_waitcnt vmcnt(0)" ::: "memory");
      __builtin_amdgcn_sched_barrier(0);
      float a0 = 0.f, a1 = 0.f;
#define PHAF(k) { unsigned hu = hv[(k) >> 3][((k) >> 1) & 3]; \
      float hvf = ((k) & 1) ? bfh(hu) : bfl(hu); \
      a0 += bfl(wtepk[k]) * hvf; \
      a1 += bfh(wtepk[k]) * hvf; }
      REP40(PHAF)
      { float hvf = bfl(hv2);
        a0 += bfl(wtepk[40]) * hvf; a1 += bfh(wtepk[40]) * hvf; }
      { float hvf = bfh(hv2);
        a0 += bfl(wtepk[41]) * hvf; a1 += bfh(wtepk[41]) * hvf; }
      block_sum2(a0, a1, &lds[OFF_RED]);
      if (tid == 0) {
        float v0 = a0 + bte0, v1 = a1 + bte1;
        v0 = v0 > 0.f ? v0 : 0.f;
        v1 = v1 > 0.f ? v1 : 0.f;
        unsigned long long tv = ((unsigned long long)__float_as_uint(v1) << 32)
                              | (unsigned long long)__float_as_uint(v0);
        __hip_atomic_store((unsigned long long*)(wste + 2 * b), tv,
                           __ATOMIC_RELAXED, __HIP_MEMORY_SCOPE_AGENT);
      }
      if (b == 0) {
        float ao = 0.f;
        if (t > 0) {
#define PAO(m) { float2 wv = *(const float2*)(P.W_out + 40 * tid + 2 * (m)); \
          unsigned hu = hv[(m) >> 2][(m) & 3]; \
          ao += wv.x * bfl(hu) + wv.y * bfh(hu); }
          REP20(PAO)
          const float* woe = P.W_out + 20480 + 2 * tid;
          ao += woe[0] * bfl(hv2) + woe[1] * bfh(hv2);
        }
        ao = block_sum(ao, &lds[OFF_RED]);
        if (tid == 0 && t > 0) P.out[t - 1] = ao + bout;
      }
    }
    ++ep; if (grid_barrier(bars, ep, b, lds)) break;

    // ---------- phase B: layer-0 ----------
    {
      float tev;
      { const float* ap = wste + tid;
        asm volatile("global_load_dword %0, %1, off sc0" : "=v"(tev) : "v"(ap)); }
      // stage ie[t] (read-only, cached)
      {
        const float4* iep4 =
            (const float4*)(ws + IE_OFF + (size_t)t * (NAG * EMB));
        float4 t40 = iep4[tid];
        float4 t41 = iep4[tid + 512];
        float4 t42 = iep4[tid + 1024];
        float4 t43 = iep4[tid + 1536];
        float4 t44 = iep4[tid + 2048];
        float4 t45 = t40;
        const bool g5 = tid < 128;
        if (g5) t45 = iep4[tid + 2560];
#define IEST(k, reg) { int i4 = tid + 512*(k); int aa = i4 >> 7; int k4 = i4 & 127; \
        *(float4*)&lds[OFF_IE + aa * IEROW + 36 * (k4 >> 3) + 4 * (k4 & 7)] = reg; }
        IEST(0, t40) IEST(1, t41) IEST(2, t42) IEST(3, t43) IEST(4, t44)
        if (g5) IEST(5, t45)
      }
      STAGE_HBF(hbase + p * 10752)          // h0[p]
      lds[OFF_TE + 36 * (tid >> 5) + (tid & 31)] = tev;
      __syncthreads();

      int laddr = bB_base;
      for (int a = 0; a < NAG; ++a) {
        float ac0 = 0.f, ac1 = 0.f, ac2 = 0.f, ac3 = 0.f;
#define DOTB(j, ac, woff, zoff) { float4 z = *(const float4*)&lds[laddr + (zoff) + 4*(j)]; \
        ac += w0[(woff)+4*(j)]*z.x;   ac += w0[(woff)+4*(j)+1]*z.y; \
        ac += w0[(woff)+4*(j)+2]*z.z; ac += w0[(woff)+4*(j)+3]*z.w; }
        DOTB(0, ac0, 0, 0)  DOTB(1, ac1, 0, 0)  DOTB(2, ac2, 0, 0)  DOTB(3, ac3, 0, 0)
        DOTB(4, ac0, 0, 0)  DOTB(5, ac1, 0, 0)  DOTB(6, ac2, 0, 0)  DOTB(7, ac3, 0, 0)
        DOTB(0, ac0, 32, 36) DOTB(1, ac1, 32, 36) DOTB(2, ac2, 32, 36) DOTB(3, ac3, 32, 36)
        DOTB(4, ac0, 32, 36) DOTB(5, ac1, 32, 36) DOTB(6, ac2, 32, 36) DOTB(7, ac3, 32, 36)
        float acc = (ac0 + ac1) + (ac2 + ac3);
        acc += __shfl_xor(acc, 16);
        acc += __shfl_xor(acc, 32);
        if (lane < 16) lds[OFF_PART + a * 144 + n * 9 + wav] = acc;
        laddr += bB_astep;
      }
      __syncthreads();
      if (tid < 84) {
        int a = tid >> 2, j = tid & 3;
        const float* pp = &lds[OFF_PART + a * 144];
        float gv0, gv1, gv2, gv3;
#define GATE(base, gg, gv) { float s = lds[(base) + 4*(gg) + j]; \
        s += pp[(4*(gg)+j)*9+0] + pp[(4*(gg)+j)*9+1] + pp[(4*(gg)+j)*9+2] + pp[(4*(gg)+j)*9+3]; \
        s += pp[(4*(gg)+j)*9+4] + pp[(4*(gg)+j)*9+5] + pp[(4*(gg)+j)*9+6] + pp[(4*(gg)+j)*9+7]; \
        gv = s; }
        GATE(OFF_B0, 0, gv0) GATE(OFF_B0, 1, gv1) GATE(OFF_B0, 2, gv2) GATE(OFF_B0, 3, gv3)
        float cn = sigf(gv1) * c0r + sigf(gv0) * tanhf(gv2);
        float hn = sigf(gv3) * tanhf(cn);
        c0r = cn; h0r = hn;
        unsigned hb16 = f2bf(hn);
        unsigned nb1 = __shfl_down(hb16, 1, 64);
        unsigned nb2 = __shfl_down(hb16, 2, 64);
        unsigned nb3 = __shfl_down(hb16, 3, 64);
        if (j == 0) {
          unsigned long long pk = (unsigned long long)hb16
            | ((unsigned long long)nb1 << 16) | ((unsigned long long)nb2 << 32)
            | ((unsigned long long)nb3 << 48);
          __hip_atomic_store((unsigned long long*)(hbase + (p ^ 1) * 10752) + (a * 256 + b),
                             pk, __ATOMIC_RELAXED, __HIP_MEMORY_SCOPE_AGENT);
        }
      }
    }
    ++ep; if (grid_barrier(bars, ep, b, lds)) break;

    // ---------- phase C: layer-1 (pass1: h0n x W_ih1; pass2: h1p x W_hh1) ----------
    {
      STAGE_HBF(hbase + (p ^ 1) * 10752)    // h0[p^1] (fresh)
      __syncthreads();
      int laddr = bC_base;
      for (int a = 0; a < NAG; ++a) {
        float ac0 = 0.f, ac1 = 0.f;
#define DOTC(j, ac, W) { float4 z = *(const float4*)&lds[laddr + 4*(j)]; \
        ac += W[4*(j)]*z.x; ac += W[4*(j)+1]*z.y; ac += W[4*(j)+2]*z.z; ac += W[4*(j)+3]*z.w; }
        DOTC(0, ac0, w1a) DOTC(1, ac1, w1a) DOTC(2, ac0, w1a) DOTC(3, ac1, w1a)
        DOTC(4, ac0, w1a) DOTC(5, ac1, w1a) DOTC(6, ac0, w1a) DOTC(7, ac1, w1a)
        float acc = ac0 + ac1;
        acc += __shfl_xor(acc, 16);
        acc += __shfl_xor(acc, 32);
        if (lane < 16) lds[OFF_PART + a * 144 + n * 9 + wav] = acc;
        laddr += HROW;
      }
      __syncthreads();
      // h1[p] re-staging WITHOUT reload: unpack hv/hv2 from phase A
      {
#define RSTB(q) { ST2(hv[q][0], 40*tid + 8*(q)) ST2(hv[q][1], 40*tid + 8*(q)+2) \
        ST2(hv[q][2], 40*tid + 8*(q)+4) ST2(hv[q][3], 40*tid + 8*(q)+6) }
        REP5(RSTB)
        ST2(hv2, 20480 + 2 * tid)
      }
      __syncthreads();
      laddr = bC_base;
      for (int a = 0; a < NAG; ++a) {
        float ac0 = 0.f, ac1 = 0.f;
        DOTC(0, ac0, w1b) DOTC(1, ac1, w1b) DOTC(2, ac0, w1b) DOTC(3, ac1, w1b)
        DOTC(4, ac0, w1b) DOTC(5, ac1, w1b) DOTC(6, ac0, w1b) DOTC(7, ac1, w1b)
        float acc = ac0 + ac1;
        acc += __shfl_xor(acc, 16);
        acc += __shfl_xor(acc, 32);
        if (lane < 16) lds[OFF_PART + a * 144 + n * 9 + wav] += acc;
        laddr += HROW;
      }
      __syncthreads();
      if (tid < 84) {
        int a = tid >> 2, j = tid & 3;
        const float* pp = &lds[OFF_PART + a * 144];
        float gv0, gv1, gv2, gv3;
        GATE(OFF_B1, 0, gv0) GATE(OFF_B1, 1, gv1) GATE(OFF_B1, 2, gv2) GATE(OFF_B1, 3, gv3)
        float cn = sigf(gv1) * c1r + sigf(gv0) * tanhf(gv2);
        float hn = sigf(gv3) * tanhf(cn);
        c1r = cn; h1r = hn;
        unsigned hb16 = f2bf(hn);
        unsigned nb1 = __shfl_down(hb16, 1, 64);
        unsigned nb2 = __shfl_down(hb16, 2, 64);
        unsigned nb3 = __shfl_down(hb16, 3, 64);
        if (j == 0) {
          unsigned long long pk = (unsigned long long)hb16
            | ((unsigned long long)nb1 << 16) | ((unsigned long long)nb2 << 32)
            | ((unsigned long long)nb3 << 48);
          __hip_atomic_store((unsigned long long*)(hbase + 21504 + (p ^ 1) * 10752) + (a * 256 + b),
                             pk, __ATOMIC_RELAXED, __HIP_MEMORY_SCOPE_AGENT);
        }
      }
    }
    ++ep; if (grid_barrier(bars, ep, b, lds)) break;
  }

  // ---------- epilogue: out[S-1] + final states from registers ----------
  if (b == 0) {
    const unsigned* h1u = hbase + 21504;    // final h1 = parity 0 (S even)
    u32x4 ev[5]; unsigned ev2;
#define ELD(q) { const u32x4* ap = (const u32x4*)(h1u + 20 * tid) + (q); \
    asm volatile("global_load_dwordx4 %0, %1, off sc0" : "=v"(ev[q]) : "v"(ap)); }
    REP5(ELD)
    { const unsigned* ap = h1u + 10240 + tid;
      asm volatile("global_load_dword %0, %1, off sc0" : "=v"(ev2) : "v"(ap)); }
    asm volatile("s_waitcnt vmcnt(0)" ::: "memory");
    __builtin_amdgcn_sched_barrier(0);
    float ao = 0.f;
#define EAO(m) { float2 wv = *(const float2*)(P.W_out + 40 * tid + 2 * (m)); \
    unsigned hu = ev[(m) >> 2][(m) & 3]; \
    ao += wv.x * bfl(hu) + wv.y * bfh(hu); }
    REP20(EAO)
    { const float* woe = P.W_out + 20480 + 2 * tid;
      ao += woe[0] * bfl(ev2) + woe[1] * bfh(ev2); }
    ao = block_sum(ao, &lds[OFF_RED]);
    if (tid == 0) P.out[SEQ - 1] = ao + bout;
  }
  if (tid < 84) {
    int a = tid >> 2, j = tid & 3;
    int idx = a * HID + 4 * b + j;
    P.out[SEQ + idx]          = h0r;
    P.out[SEQ + NH + idx]     = h1r;
    P.out[SEQ + 2*NH + idx]   = c0r;
    P.out[SEQ + 3*NH + idx]   = c1r;
  }
}

extern "C" void kernel_launch(void* const* d_in, const int* in_sizes, int n_in,
                              void* d_out, int out_size, void* d_ws, size_t ws_size,
                              hipStream_t stream) {
  (void)in_sizes; (void)n_in; (void)out_size; (void)ws_size;
  Params P;
  P.x     = (const float*)d_in[0];
  P.W_ie  = (const float*)d_in[1];
  P.b_ie  = (const float*)d_in[2];
  P.W_te  = (const float*)d_in[3];
  P.b_te  = (const float*)d_in[4];
  P.W_ih0 = (const float*)d_in[5];
  P.W_hh0 = (const float*)d_in[6];
  P.b_ih0 = (const float*)d_in[7];
  P.b_hh0 = (const float*)d_in[8];
  P.W_ih1 = (const float*)d_in[9];
  P.W_hh1 = (const float*)d_in[10];
  P.b_ih1 = (const float*)d_in[11];
  P.b_hh1 = (const float*)d_in[12];
  P.W_out = (const float*)d_in[13];
  P.b_out = (const float*)d_in[14];
  P.out   = (float*)d_out;
  P.ws    = (float*)d_ws;

  sl_init<<<64, HTHR, 0, stream>>>((float*)d_ws);
  sl_ie<<<SEQ, HTHR, 0, stream>>>(P.x, P.W_ie, P.b_ie, (float*)d_ws);

  void* args[] = { &P };
  hipLaunchCooperativeKernel((const void*)sl_main, dim3(NBLK), dim3(NTHR),
                             args, 0, stream);
}